// Round 5
// baseline (284.833 us; speedup 1.0000x reference)
//
#include <hip/hip_runtime.h>
#include <hip/hip_bf16.h>

// ===================== Round 13: barrier-free, LDS-free GEMM ===================
// R12 (fused + hand-rolled grid barrier) hung -> reverted to R11's two-kernel
// shell (passed). Residual ~112us is harness-owned (invariant to our nodes,
// R9-R11). Remaining target: gemm 122us with ALL pipes <=16%.
// Theory: per-step latency convoy. R8/R9/R10 (different LDS/barrier structures)
// all ~120us: the shared trait is loads consumed one barrier-period after
// issue + whole-block resync every ~500cy of work -> tiny in-flight memory ->
// Little's-law idle. N=600 is tiny and B is already direct-to-reg; A's LDS
// staging (the only reason barriers exist) can go too: each wave loads its own
// A fragments straight from X (row=wm+i*16+lrow, k-octet=quad*8 — the same
// pattern as the old LDS read) and converts fp32->bf16 in-register. K-loop:
// ZERO barriers, ZERO LDS, explicit 2-deep named register double-buffer.
// Duplicate A/B loads across wave pairs are L1 hits; unique L2 bytes/step
// unchanged -> clean experiment on sync structure alone.
// kc=96 guarded per-element vs KDIM (kidx=1 only); kc=97 all-zero W: skipped.
// Math/MFMA order identical -> absmax must stay 0.001953125.
// Predicted: LDS 18432->0, conflicts 2.0M->~0, MfmaUtil 10->20-30%,
// gemm 122 -> 50-75us. If ~120 again: limiter is traffic, not sync -> pivot.

#define NFFT   512
#define HOP    128
#define KDIM   3084      // 257*6*2
#define KP     3136      // K padded (49*64)
#define NOUT   600
#define NP     640       // W rows padded (5*128)
#define BM     64
#define BN     128

#define NFRAG_K 98       // KP/32 k-chunks
#define FRAG_SH 512      // shorts per fragment (64 lanes x 8)
#define WTOT    ((size_t)(NP / 16) * NFRAG_K * FRAG_SH)  // 4.01 MB

typedef short s16x8 __attribute__((ext_vector_type(8)));
typedef float f32x4 __attribute__((ext_vector_type(4)));

static __device__ __forceinline__ unsigned short bf16_bits(float f) {
    __hip_bfloat16 b = __float2bfloat16(f);   // RNE - R4-verified path
    return *(unsigned short*)&b;
}

static __device__ __forceinline__ s16x8 cvt_frag(float4 lo, float4 hi) {
    s16x8 r;
    r[0] = (short)bf16_bits(lo.x); r[1] = (short)bf16_bits(lo.y);
    r[2] = (short)bf16_bits(lo.z); r[3] = (short)bf16_bits(lo.w);
    r[4] = (short)bf16_bits(hi.x); r[5] = (short)bf16_bits(hi.y);
    r[6] = (short)bf16_bits(hi.z); r[7] = (short)bf16_bits(hi.w);
    return r;
}

// ---------------- W generation (fragment layout) + out zeroing ---------------
// Fragment (n16, kc) holds W[n16*16 + (l&15)][kc*32 + (l>>4)*8 + e] at
// shorts offset ((n16*98 + kc)*64 + l)*8 + e. Row n is block l's rowbuf.
// (unchanged from R11 — passed)
__global__ __launch_bounds__(256) void gen_W(unsigned short* __restrict__ Wt,
                                             float4* __restrict__ outZ,
                                             int nvec4) {
    __shared__ float costab[512];
    __shared__ __align__(16) unsigned short rowbuf[KP];   // 6272 B
    const int l   = blockIdx.x;     // 0..639  (row n = l)
    const int tid = threadIdx.x;
    const float w0 = 6.283185307179586f / 512.0f;

    // zero the output buffer in-kernel (replaces the SDMA memset)
    for (int i = blockIdx.x * 256 + tid; i < nvec4; i += NP * 256)
        outZ[i] = make_float4(0.f, 0.f, 0.f, 0.f);

    *(int4*)(rowbuf + tid * 8) = make_int4(0, 0, 0, 0);
    if (tid < 136) *(int4*)(rowbuf + (256 + tid) * 8) = make_int4(0, 0, 0, 0);
    costab[tid]       = __cosf((float)tid * w0);
    costab[tid + 256] = __cosf((float)(tid + 256) * w0);
    __syncthreads();

    if (l < NOUT) {
        const int p = l + 256;
        float env = 0.0f;
#pragma unroll
        for (int tt = 0; tt < 6; ++tt) {
            int m = p - HOP * tt;
            if (m >= 0 && m < NFFT) {
                float w = 0.5f - 0.5f * costab[m];
                env += w * w;
            }
        }
        const float inv = 1.0f / (512.0f * env);
        for (int f = tid; f <= 256; f += 256) {
            float cf = (f == 0 || f == 256) ? 1.0f : 2.0f;
#pragma unroll
            for (int t = 0; t < 6; ++t) {
                int n = p - HOP * t;
                if (n >= 0 && n < NFFT) {
                    float w = 0.5f - 0.5f * costab[n];
                    float scale = cf * w * inv;
                    int a = (f * n) & 511;
                    float c = costab[a];
                    float s = costab[(a + 384) & 511];
                    rowbuf[f * 12 + t * 2 + 0] = bf16_bits(scale * c);
                    rowbuf[f * 12 + t * 2 + 1] = bf16_bits(-scale * s);
                }
            }
        }
    }
    __syncthreads();

    // scatter row n=l into fragment layout: 392 units of 16B (kc 0..97, q 0..3)
    const int n16 = l >> 4, r = l & 15;
    for (int u = tid; u < 392; u += 256) {
        const int kc = u >> 2, q = u & 3;
        int4 val = *(const int4*)(rowbuf + kc * 32 + q * 8);
        *(int4*)(Wt + (((size_t)n16 * NFRAG_K + kc) * 64 + q * 16 + r) * 8) = val;
    }
}

// ---------------- GEMM: out += X * W^T (split-K halves) ----------------------
// 256 thr = 4 waves, wave tile 32(m) x 64(n); grid 1280 = 128mt x 5nt x 2k.
// No LDS, no barriers: A fragments loaded per-wave straight from X (fp32),
// converted in-register; B fragments direct from pre-swizzled W. 2-deep
// named register double-buffer (set0/set1), kc (K=32) granularity.
__global__ __launch_bounds__(256, 4) void gemm_kernel(
        const float* __restrict__ X,           // fp32 [8192][3084]
        const unsigned short* __restrict__ Wt, // bf16 frags, WTOT shorts
        float* __restrict__ out) {             // fp32 [8192][600], pre-zeroed
    const int tid = threadIdx.x;
    // XCD swizzle: the 10 blocks (5 nt x 2 kidx) of one mt share an XCD.
    const int bid  = blockIdx.x;           // 0..1279
    const int xcd  = bid & 7;
    const int rest = bid >> 3;             // 0..159
    const int mt   = xcd * 16 + rest / 10; // 0..127
    const int sub  = rest % 10;
    const int nt   = sub >> 1;             // 0..4
    const int kidx = sub & 1;              // 0/1
    const int mBase = mt * BM;
    const int nBase = nt * BN;

    const int lane = tid & 63;
    const int wave = tid >> 6;
    const int wm   = (wave & 1) * 32;
    const int wn   = (wave >> 1) * 64;
    const int lrow = lane & 15;
    const int quad = lane >> 4;

    // A fragment rows for this lane (two 16-row groups of the wave's 32 rows)
    const float* aRow0 = X + (size_t)(mBase + wm + lrow) * KDIM;
    const float* aRow1 = aRow0 + (size_t)16 * KDIM;
    const int kq = quad * 8;               // lane's k-octet within a kc chunk

    // B fragment base for this wave: n16 row-block = nt*8 + (wave>>1)*4 + j
    const int n16base = nt * 8 + (wave >> 1) * 4;
    const unsigned short* wB0 = Wt + (size_t)n16base * NFRAG_K * FRAG_SH
                                   + (size_t)lane * 8;

    f32x4 acc[2][4];
#pragma unroll
    for (int i = 0; i < 2; ++i)
#pragma unroll
        for (int j = 0; j < 4; ++j) acc[i][j] = (f32x4){0.f, 0.f, 0.f, 0.f};

#define LOADA(L0, H0, L1, H1, kc_)                                             \
    {                                                                          \
        const int kb_ = (kc_) * 32 + kq;                                       \
        L0 = *(const float4*)(aRow0 + kb_);                                    \
        H0 = *(const float4*)(aRow0 + kb_ + 4);                                \
        L1 = *(const float4*)(aRow1 + kb_);                                    \
        H1 = *(const float4*)(aRow1 + kb_ + 4);                                \
    }

#define LOADB(BV, kc_)                                                         \
    {                                                                          \
        _Pragma("unroll")                                                      \
        for (int j = 0; j < 4; ++j)                                            \
            BV[j] = *(const s16x8*)(const void*)(wB0 +                         \
                        ((size_t)j * NFRAG_K + (size_t)(kc_)) * FRAG_SH);      \
    }

#define COMPUTE(L0, H0, L1, H1, BV)                                            \
    {                                                                          \
        s16x8 af0 = cvt_frag(L0, H0);                                          \
        s16x8 af1 = cvt_frag(L1, H1);                                          \
        _Pragma("unroll")                                                      \
        for (int j = 0; j < 4; ++j)                                            \
            acc[0][j] = __builtin_amdgcn_mfma_f32_16x16x32_bf16(               \
                af0, BV[j], acc[0][j], 0, 0, 0);                               \
        _Pragma("unroll")                                                      \
        for (int j = 0; j < 4; ++j)                                            \
            acc[1][j] = __builtin_amdgcn_mfma_f32_16x16x32_bf16(               \
                af1, BV[j], acc[1][j], 0, 0, 0);                               \
    }

    // kc ranges: kidx=0 -> [0,50) clean; kidx=1 -> [50,96) clean + kc=96 tail
    // (kc=97 skipped: W pad rows are all-zero there by construction)
    const int kcBeg = kidx ? 50 : 0;
    const int kcEnd = kidx ? 96 : 50;     // both ranges have even length

    float4 a0l0, a0h0, a1l0, a1h0;        // set0 (named regs, rule #20)
    float4 a0l1, a0h1, a1l1, a1h1;        // set1
    s16x8  bv0[4], bv1[4];

    LOADA(a0l0, a0h0, a1l0, a1h0, kcBeg);
    LOADB(bv0, kcBeg);
    for (int kc = kcBeg; kc + 1 < kcEnd; kc += 2) {
        LOADA(a0l1, a0h1, a1l1, a1h1, kc + 1);
        LOADB(bv1, kc + 1);
        COMPUTE(a0l0, a0h0, a1l0, a1h0, bv0);
        if (kc + 2 < kcEnd) {
            LOADA(a0l0, a0h0, a1l0, a1h0, kc + 2);
            LOADB(bv0, kc + 2);
        }
        COMPUTE(a0l1, a0h1, a1l1, a1h1, bv1);
    }

    if (kidx) {
        // kc = 96: k in [3072,3104) crosses KDIM=3084 -> per-element guard.
        const int kb = 96 * 32 + kq;
        float e0[8], e1[8];
#pragma unroll
        for (int e = 0; e < 8; ++e) {
            const int k = kb + e;
            const bool ok = (k < KDIM);
            e0[e] = ok ? aRow0[k] : 0.f;
            e1[e] = ok ? aRow1[k] : 0.f;
        }
        float4 l0 = make_float4(e0[0], e0[1], e0[2], e0[3]);
        float4 h0 = make_float4(e0[4], e0[5], e0[6], e0[7]);
        float4 l1 = make_float4(e1[0], e1[1], e1[2], e1[3]);
        float4 h1 = make_float4(e1[4], e1[5], e1[6], e1[7]);
        LOADB(bv0, 96);
        COMPUTE(l0, h0, l1, h1, bv0);
    }

#undef LOADA
#undef LOADB
#undef COMPUTE

    // ---- epilogue: H1 layout (n=lane&15, m=quad*4+reg), atomic accumulate
#pragma unroll
    for (int i = 0; i < 2; ++i) {
#pragma unroll
        for (int j = 0; j < 4; ++j) {
            int gn = nBase + wn + j * 16 + lrow;
            if (gn < NOUT) {
#pragma unroll
                for (int r = 0; r < 4; ++r) {
                    int gm = mBase + wm + i * 16 + quad * 4 + r;
                    atomicAdd(out + (size_t)gm * NOUT + gn, acc[i][j][r]);
                }
            }
        }
    }
}

extern "C" void kernel_launch(void* const* d_in, const int* in_sizes, int n_in,
                              void* d_out, int out_size, void* d_ws, size_t ws_size,
                              hipStream_t stream) {
    const float* X = (const float*)d_in[0];
    unsigned short* W = (unsigned short*)d_ws;   // bf16 fragment layout, 4.01 MB
    float* out = (float*)d_out;

    gen_W<<<dim3(NP), 256, 0, stream>>>(W, (float4*)d_out, out_size / 4);
    gemm_kernel<<<dim3(128 * 5 * 2), 256, 0, stream>>>(X, W, out);
}